// Round 1
// baseline (774.893 us; speedup 1.0000x reference)
//
#include <hip/hip_runtime.h>
#include <math.h>

#define Dv 1024
#define Ev 8
#define Hv 2816
#define Nv 4096
#define NKv 8192
#define CAPv 1280
#define TH2v 5632

typedef unsigned short u16;
typedef __attribute__((ext_vector_type(8))) short s16x8;
typedef __attribute__((ext_vector_type(4))) float f32x4;
typedef __attribute__((ext_vector_type(8))) u16 u16x8;
typedef __attribute__((ext_vector_type(4))) u16 u16x4;

typedef const __attribute__((address_space(1))) void* as1_cvp;
typedef __attribute__((address_space(3))) void* as3_vp;

__device__ __forceinline__ u16 f2bf(float f) {
  unsigned u = __float_as_uint(f);
  u += 0x7fffu + ((u >> 16) & 1u);
  return (u16)(u >> 16);
}
__device__ __forceinline__ float bf2f(u16 h) {
  return __uint_as_float(((unsigned)h) << 16);
}
__device__ __forceinline__ void gload16(const void* g, void* l) {
  __builtin_amdgcn_global_load_lds((as1_cvp)g, (as3_vp)l, 16, 0, 0);
}

// ---------------- router: logits fp32 exact, top-2, probs, aux partials ----------------
__global__ __launch_bounds__(256) void router_kernel(
    const float* __restrict__ x, const float* __restrict__ gw,
    int* __restrict__ tkidx, float* __restrict__ tkprob,
    float* __restrict__ red, float* __restrict__ outIdx)
{
  __shared__ float lred[17];
  int tid = threadIdx.x;
  if (tid < 17) lred[tid] = 0.f;
  __syncthreads();
  int wv = tid >> 6, ln = tid & 63;
  int n = blockIdx.x * 4 + wv;
  float a[8] = {0.f,0.f,0.f,0.f,0.f,0.f,0.f,0.f};
  const float* xr = x + (size_t)n * Dv;
  #pragma unroll
  for (int it = 0; it < 16; ++it) {
    int d = ln + it * 64;
    float xs = xr[d];
    float4 g0 = *(const float4*)(gw + (size_t)d * 8);
    float4 g1 = *(const float4*)(gw + (size_t)d * 8 + 4);
    a[0] += xs * g0.x; a[1] += xs * g0.y; a[2] += xs * g0.z; a[3] += xs * g0.w;
    a[4] += xs * g1.x; a[5] += xs * g1.y; a[6] += xs * g1.z; a[7] += xs * g1.w;
  }
  #pragma unroll
  for (int off = 32; off >= 1; off >>= 1) {
    #pragma unroll
    for (int e = 0; e < 8; ++e) a[e] += __shfl_xor(a[e], off, 64);
  }
  // top-2, first-max tie rule (matches lax.top_k / argmax)
  int i1 = 0; float v1 = a[0];
  #pragma unroll
  for (int e = 1; e < 8; ++e) if (a[e] > v1) { v1 = a[e]; i1 = e; }
  int i2 = -1; float v2 = -1e30f;
  #pragma unroll
  for (int e = 0; e < 8; ++e) if (e != i1 && a[e] > v2) { v2 = a[e]; i2 = e; }
  float Z = 0.f;
  #pragma unroll
  for (int e = 0; e < 8; ++e) Z += expf(a[e] - v1);
  float zlse = v1 + logf(Z);
  float t = expf(v2 - v1);
  float p1 = 1.f / (1.f + t);
  float p2 = t * p1;
  if (ln == 0) {
    tkidx[2*n] = i1; tkidx[2*n+1] = i2;
    tkprob[2*n] = p1; tkprob[2*n+1] = p2;
    outIdx[2*n] = (float)i1; outIdx[2*n+1] = (float)i2;
    #pragma unroll
    for (int e = 0; e < 8; ++e) atomicAdd(&lred[e], expf(a[e] - v1) / Z);
    atomicAdd(&lred[8 + i1], 1.f);
    atomicAdd(&lred[16], zlse * zlse);
  }
  __syncthreads();
  if (tid < 17) atomicAdd(&red[tid], lred[tid]);
}

__global__ void aux_kernel(const float* __restrict__ red, float* __restrict__ outAux) {
  float bl = 0.f;
  for (int e = 0; e < 8; ++e) bl += (red[e] / (float)Nv) * (red[8 + e] / (float)Nv);
  bl *= (float)Ev;
  float zl = red[16] / (float)Nv;
  outAux[0] = 0.01f * bl + 0.001f * zl;
}

// ---------------- exact stable rank within expert (NK order) ----------------
__global__ __launch_bounds__(256) void rank_kernel(const int* __restrict__ tgt,
    int* __restrict__ keep, int* __restrict__ dstNK)
{
  __shared__ int hist[256][8];
  int t = threadIdx.x;
  int h[8] = {0,0,0,0,0,0,0,0};
  int base = t * 32;
  for (int j = 0; j < 32; ++j) h[tgt[base + j]]++;
  for (int e = 0; e < 8; ++e) hist[t][e] = h[e];
  __syncthreads();
  if (t < 8) {
    int run = 0;
    for (int tt = 0; tt < 256; ++tt) { int v = hist[tt][t]; hist[tt][t] = run; run += v; }
  }
  __syncthreads();
  for (int e = 0; e < 8; ++e) h[e] = hist[t][e];
  for (int j = 0; j < 32; ++j) {
    int i = base + j; int e = tgt[i]; int r = h[e]++;
    int kp = (r < CAPv) ? 1 : 0;
    keep[i] = kp;
    if (kp) dstNK[e * CAPv + r] = i;
  }
}

// ---------------- pack expert buffer (f32 -> bf16), zeros for empty slots ----------------
__global__ __launch_bounds__(256) void pack_kernel(const float* __restrict__ x,
    const int* __restrict__ dstNK, u16* __restrict__ buf)
{
  int s = blockIdx.x * 4 + (threadIdx.x >> 6);
  int ln = threadIdx.x & 63;
  int i = dstNK[s];
  u16* dst = buf + (size_t)s * Dv;
  if (i >= 0) {
    const float* src = x + (size_t)(i >> 1) * Dv;
    #pragma unroll
    for (int j = 0; j < 2; ++j) {
      int d0 = ln * 16 + j * 8;
      float4 v0 = *(const float4*)(src + d0);
      float4 v1 = *(const float4*)(src + d0 + 4);
      u16x8 o;
      o[0]=f2bf(v0.x); o[1]=f2bf(v0.y); o[2]=f2bf(v0.z); o[3]=f2bf(v0.w);
      o[4]=f2bf(v1.x); o[5]=f2bf(v1.y); o[6]=f2bf(v1.z); o[7]=f2bf(v1.w);
      *(u16x8*)(dst + d0) = o;
    }
  } else {
    u16x8 z = {0,0,0,0,0,0,0,0};
    *(u16x8*)(dst + ln * 16) = z;
    *(u16x8*)(dst + ln * 16 + 8) = z;
  }
}

// ---------------- transpose + fp32->bf16: in [R][C] f32 -> out [C][R] bf16 ----------------
__global__ __launch_bounds__(256) void tconv_kernel(const float* __restrict__ in,
    u16* __restrict__ out, int R, int C)
{
  __shared__ u16 tile[64][68];
  size_t zoff = (size_t)blockIdx.z * (size_t)R * (size_t)C;
  in += zoff; out += zoff;
  int r0 = blockIdx.y * 64, c0 = blockIdx.x * 64;
  int t = threadIdx.x;
  int cc4 = (t & 15) * 4;
  #pragma unroll
  for (int p = 0; p < 4; ++p) {
    int r = (t >> 4) + p * 16;
    float4 v = *(const float4*)(in + (size_t)(r0 + r) * C + c0 + cc4);
    u16x4 b; b[0]=f2bf(v.x); b[1]=f2bf(v.y); b[2]=f2bf(v.z); b[3]=f2bf(v.w);
    *(u16x4*)(&tile[r][cc4]) = b;
  }
  __syncthreads();
  int rr4 = (t & 15) * 4;
  #pragma unroll
  for (int p = 0; p < 4; ++p) {
    int c = (t >> 4) + p * 16;
    u16x4 o; o[0]=tile[rr4][c]; o[1]=tile[rr4+1][c]; o[2]=tile[rr4+2][c]; o[3]=tile[rr4+3][c];
    *(u16x4*)(out + (size_t)(c0 + c) * R + r0 + rr4) = o;
  }
}

// ---------------- 128x128 bf16 MFMA GEMM, NT (A [M][K], B' [N][K]), BK=64 ----------------
// MODE 0: store bf16 C[M][N]   1: SwiGLU (gate=cols tn*64.., up=+H) -> act bf16
// MODE 2: scatter rows via dstNK -> sel   3: gelu -> bf16   4: store f32
template<int MODE>
__global__ __launch_bounds__(256) void gemm128(
    const u16* __restrict__ A, const u16* __restrict__ A2, int splitK,
    const u16* __restrict__ B, void* __restrict__ C,
    const int* __restrict__ dst,
    int Ksz, int lda, int ldb, int ldc, int ntm,
    size_t sA, size_t sB, size_t sC)
{
  __shared__ char smem[32768];
  int e = blockIdx.y;
  int bid = blockIdx.x;
  int tm = bid % ntm, tn = bid / ntm;
  const u16* Ae  = A  + (size_t)e * sA;
  const u16* A2e = A2 + (size_t)e * sA;
  const u16* Be  = B  + (size_t)e * sB;
  int tid = threadIdx.x, wv = tid >> 6, ln = tid & 63;

  const char* aP[4]; const char* a2P[4]; const char* bP[4];
  unsigned aL[4], bL[4];
  #pragma unroll
  for (int r = 0; r < 4; ++r) {
    int lb = r * 4096 + tid * 16;
    int row = lb >> 7;
    int colb = (lb & 127) ^ ((row & 7) << 4);
    aP[r]  = (const char*)(Ae  + (size_t)(tm * 128 + row) * lda) + colb;
    a2P[r] = (const char*)(A2e + (size_t)(tm * 128 + row) * lda) + colb;
    int brow;
    if (MODE == 1) {
      int j = tn * 64;
      brow = (row < 64) ? (j + row) : (Hv + j + (row - 64));
    } else {
      brow = tn * 128 + row;
    }
    bP[r] = (const char*)(Be + (size_t)brow * ldb) + colb;
    aL[r] = r * 4096 + wv * 1024;
    bL[r] = 16384 + r * 4096 + wv * 1024;
  }

  f32x4 acc[2][8];
  #pragma unroll
  for (int m = 0; m < 2; ++m)
    #pragma unroll
    for (int n = 0; n < 8; ++n) acc[m][n] = (f32x4){0.f, 0.f, 0.f, 0.f};

  for (int k0 = 0; k0 < Ksz; k0 += 64) {
    size_t kb = (size_t)k0 * 2;
    bool p2 = (k0 >= splitK);
    size_t kb2 = p2 ? (size_t)(k0 - splitK) * 2 : kb;
    #pragma unroll
    for (int r = 0; r < 4; ++r)
      gload16((p2 ? a2P[r] : aP[r]) + kb2, smem + aL[r]);
    #pragma unroll
    for (int r = 0; r < 4; ++r)
      gload16(bP[r] + kb, smem + bL[r]);
    __syncthreads();
    #pragma unroll
    for (int ks = 0; ks < 2; ++ks) {
      int kbyte = ks * 64 + ((ln >> 4) << 4);
      s16x8 av[2];
      #pragma unroll
      for (int m = 0; m < 2; ++m) {
        int row = wv * 32 + m * 16 + (ln & 15);
        av[m] = *(const s16x8*)(smem + (row << 7) + (kbyte ^ ((row & 7) << 4)));
      }
      #pragma unroll
      for (int n = 0; n < 8; ++n) {
        int row = n * 16 + (ln & 15);
        s16x8 bv = *(const s16x8*)(smem + 16384 + (row << 7) + (kbyte ^ ((row & 7) << 4)));
        acc[0][n] = __builtin_amdgcn_mfma_f32_16x16x32_bf16(av[0], bv, acc[0][n], 0, 0, 0);
        acc[1][n] = __builtin_amdgcn_mfma_f32_16x16x32_bf16(av[1], bv, acc[1][n], 0, 0, 0);
      }
    }
    __syncthreads();
  }

  int rbase = tm * 128 + wv * 32 + ((ln >> 4) << 2);
  int cb = (ln & 15);
  if (MODE == 0) {
    u16* Cp = (u16*)C + (size_t)e * sC;
    #pragma unroll
    for (int m = 0; m < 2; ++m)
      #pragma unroll
      for (int n = 0; n < 8; ++n)
        #pragma unroll
        for (int v = 0; v < 4; ++v)
          Cp[(size_t)(rbase + m * 16 + v) * ldc + tn * 128 + n * 16 + cb] = f2bf(acc[m][n][v]);
  } else if (MODE == 1) {
    u16* Cp = (u16*)C + (size_t)e * sC;
    #pragma unroll
    for (int m = 0; m < 2; ++m)
      #pragma unroll
      for (int n = 0; n < 4; ++n)
        #pragma unroll
        for (int v = 0; v < 4; ++v) {
          float g = acc[m][n][v];
          float u = acc[m][n + 4][v];
          float sg = g / (1.f + __expf(-g));
          Cp[(size_t)(rbase + m * 16 + v) * ldc + tn * 64 + n * 16 + cb] = f2bf(sg * u);
        }
  } else if (MODE == 2) {
    u16* Cp = (u16*)C;
    #pragma unroll
    for (int m = 0; m < 2; ++m)
      #pragma unroll
      for (int v = 0; v < 4; ++v) {
        int gr = rbase + m * 16 + v;
        int i = dst[e * CAPv + gr];
        if (i >= 0) {
          #pragma unroll
          for (int n = 0; n < 8; ++n)
            Cp[(size_t)i * Dv + tn * 128 + n * 16 + cb] = f2bf(acc[m][n][v]);
        }
      }
  } else if (MODE == 3) {
    u16* Cp = (u16*)C;
    #pragma unroll
    for (int m = 0; m < 2; ++m)
      #pragma unroll
      for (int n = 0; n < 8; ++n)
        #pragma unroll
        for (int v = 0; v < 4; ++v) {
          float xg = acc[m][n][v];
          float gl = 0.5f * xg * (1.f + erff(xg * 0.70710678118654752f));
          Cp[(size_t)(rbase + m * 16 + v) * ldc + tn * 128 + n * 16 + cb] = f2bf(gl);
        }
  } else {
    float* Cp = (float*)C;
    #pragma unroll
    for (int m = 0; m < 2; ++m)
      #pragma unroll
      for (int n = 0; n < 8; ++n)
        #pragma unroll
        for (int v = 0; v < 4; ++v)
          Cp[(size_t)(rbase + m * 16 + v) * ldc + tn * 128 + n * 16 + cb] = acc[m][n][v];
  }
}

// ---------------- per-token scores + masked softmax + Cmsg ----------------
__global__ __launch_bounds__(256) void scores_kernel(
    const u16* __restrict__ Qb, const u16* __restrict__ Kkb, const u16* __restrict__ Mb,
    const int* __restrict__ keep, u16* __restrict__ Cmsg)
{
  int wv = threadIdx.x >> 6, ln = threadIdx.x & 63;
  int n = blockIdx.x * 4 + wv;
  const u16* q0 = Qb + (size_t)n * 2048;
  const u16* q1 = q0 + 1024;
  const u16* k0p = Kkb + (size_t)n * 2048;
  const u16* k1p = k0p + 1024;
  float s00 = 0, s01 = 0, s10 = 0, s11 = 0;
  #pragma unroll
  for (int j = 0; j < 2; ++j) {
    int d0 = ln * 16 + j * 8;
    u16x8 a0 = *(const u16x8*)(q0 + d0);
    u16x8 a1 = *(const u16x8*)(q1 + d0);
    u16x8 b0 = *(const u16x8*)(k0p + d0);
    u16x8 b1 = *(const u16x8*)(k1p + d0);
    #pragma unroll
    for (int t = 0; t < 8; ++t) {
      float fa0 = bf2f(a0[t]), fa1 = bf2f(a1[t]);
      float fb0 = bf2f(b0[t]), fb1 = bf2f(b1[t]);
      s00 += fa0 * fb0; s01 += fa0 * fb1; s10 += fa1 * fb0; s11 += fa1 * fb1;
    }
  }
  #pragma unroll
  for (int off = 32; off >= 1; off >>= 1) {
    s00 += __shfl_xor(s00, off, 64);
    s01 += __shfl_xor(s01, off, 64);
    s10 += __shfl_xor(s10, off, 64);
    s11 += __shfl_xor(s11, off, 64);
  }
  const float inv = 0.03125f; // 1/sqrt(1024)
  int kp0 = keep[2 * n], kp1 = keep[2 * n + 1];
  float A00, A01, A10, A11;
  {
    float v0 = kp0 ? s00 * inv : -1e9f;
    float v1 = (kp0 && kp1) ? s01 * inv : -1e9f;
    float mx = fmaxf(v0, v1);
    float e0 = expf(v0 - mx), e1 = expf(v1 - mx);
    float den = e0 + e1;
    float a0 = kp0 ? e0 / den : 0.f;
    float a1 = (kp0 && kp1) ? e1 / den : 0.f;
    float s = fmaxf(a0 + a1, 1e-12f);
    A00 = a0 / s; A01 = a1 / s;
  }
  {
    float v0 = (kp1 && kp0) ? s10 * inv : -1e9f;
    float v1 = kp1 ? s11 * inv : -1e9f;
    float mx = fmaxf(v0, v1);
    float e0 = expf(v0 - mx), e1 = expf(v1 - mx);
    float den = e0 + e1;
    float a0 = (kp1 && kp0) ? e0 / den : 0.f;
    float a1 = kp1 ? e1 / den : 0.f;
    float s = fmaxf(a0 + a1, 1e-12f);
    A10 = a0 / s; A11 = a1 / s;
  }
  const u16* m0 = Mb + (size_t)n * 2048;
  const u16* m1 = m0 + 1024;
  u16* c0 = Cmsg + (size_t)n * 2048;
  u16* c1 = c0 + 1024;
  #pragma unroll
  for (int j = 0; j < 2; ++j) {
    int d0 = ln * 16 + j * 8;
    u16x8 x0 = *(const u16x8*)(m0 + d0);
    u16x8 x1 = *(const u16x8*)(m1 + d0);
    u16x8 o0, o1;
    #pragma unroll
    for (int t = 0; t < 8; ++t) {
      float f0 = bf2f(x0[t]), f1 = bf2f(x1[t]);
      o0[t] = f2bf(A00 * f0 + A01 * f1);
      o1[t] = f2bf(A10 * f0 + A11 * f1);
    }
    *(u16x8*)(c0 + d0) = o0;
    *(u16x8*)(c1 + d0) = o1;
  }
}

// ---------------- refined = (sel+upd)*kept; fused_pre = sum_k w_k * refined ----------------
__global__ __launch_bounds__(256) void combine_kernel(
    const u16* __restrict__ sel, const u16* __restrict__ upd,
    const int* __restrict__ keep, const float* __restrict__ tkprob,
    u16* __restrict__ fusedp)
{
  int n = blockIdx.x;
  int t = threadIdx.x;
  float kp0 = keep[2 * n] ? 1.f : 0.f, kp1 = keep[2 * n + 1] ? 1.f : 0.f;
  float p0 = tkprob[2 * n] * kp0, p1 = tkprob[2 * n + 1] * kp1;
  float s = fmaxf(p0 + p1, 1e-12f);
  float w0 = p0 / s, w1 = p1 / s;
  int d0 = t * 4;
  u16x4 s0 = *(const u16x4*)(sel + (size_t)(2 * n) * Dv + d0);
  u16x4 s1 = *(const u16x4*)(sel + (size_t)(2 * n + 1) * Dv + d0);
  u16x4 u0 = *(const u16x4*)(upd + (size_t)(2 * n) * Dv + d0);
  u16x4 u1 = *(const u16x4*)(upd + (size_t)(2 * n + 1) * Dv + d0);
  u16x4 o;
  #pragma unroll
  for (int j = 0; j < 4; ++j) {
    float r0 = (bf2f(s0[j]) + bf2f(u0[j])) * kp0;
    float r1 = (bf2f(s1[j]) + bf2f(u1[j])) * kp1;
    o[j] = f2bf(w0 * r0 + w1 * r1);
  }
  *(u16x4*)(fusedp + (size_t)n * Dv + d0) = o;
}

extern "C" void kernel_launch(void* const* d_in, const int* in_sizes, int n_in,
                              void* d_out, int out_size, void* d_ws, size_t ws_size,
                              hipStream_t stream) {
  const float* x      = (const float*)d_in[0];
  const float* gate_w = (const float*)d_in[1];
  const float* w13    = (const float*)d_in[2];
  const float* w2     = (const float*)d_in[3];
  const float* msg_w  = (const float*)d_in[4];
  const float* q_w    = (const float*)d_in[5];
  const float* k_w    = (const float*)d_in[6];
  const float* upd_w1 = (const float*)d_in[7];
  const float* upd_w2 = (const float*)d_in[8];
  const float* o_w    = (const float*)d_in[9];
  float* out = (float*)d_out;
  float* outAux = out + (size_t)Nv * Dv;
  float* outIdx = outAux + 1;

  char* ws = (char*)d_ws;
  const size_t MBc = 1ull << 20;
  int*   tkidx  = (int*)(ws + 0);
  float* tkprob = (float*)(ws + 32768);
  int*   keepA  = (int*)(ws + 65536);
  int*   dstNK  = (int*)(ws + 98304);
  float* red    = (float*)(ws + 143360);
  u16* msgb   = (u16*)(ws + 1 * MBc);
  u16* qb     = (u16*)(ws + 3 * MBc);
  u16* kb     = (u16*)(ws + 5 * MBc);
  u16* ob     = (u16*)(ws + 7 * MBc);
  u16* upd1b  = (u16*)(ws + 9 * MBc);
  u16* upd2b  = (u16*)(ws + 17 * MBc);
  u16* SEL    = (u16*)(ws + 21 * MBc);
  u16* CMSG   = (u16*)(ws + 37 * MBc);
  u16* UPDp   = CMSG;                    // reuse: CMSG dead after upd1 GEMM
  u16* FUSEDP = (u16*)(ws + 53 * MBc);
  u16* BUF    = (u16*)(ws + 61 * MBc);
  u16* ACT    = (u16*)(ws + 81 * MBc);   // 57.7 MiB, dead after G2
  u16* G1B    = (u16*)(ws + 81 * MBc);   // reuse ACT space after G2
  u16* W13Be  = (u16*)(ws + 139 * MBc);  // 11 MiB rotating per-expert
  u16* W2B    = (u16*)(ws + 139 * MBc);  // 44 MiB, after G1
  u16* MBUF   = (u16*)(ws + 139 * MBc);  // after G2
  u16* QBUF   = (u16*)(ws + 155 * MBc);
  u16* KKBUF  = (u16*)(ws + 171 * MBc);  // peak: 187 MiB

  hipMemsetAsync(red, 0, 68, stream);
  hipMemsetAsync(dstNK, 0xFF, Ev * CAPv * 4, stream);
  hipMemsetAsync(SEL, 0, (size_t)NKv * Dv * 2, stream);

  router_kernel<<<Nv / 4, 256, 0, stream>>>(x, gate_w, tkidx, tkprob, red, outIdx);
  aux_kernel<<<1, 1, 0, stream>>>(red, outAux);
  rank_kernel<<<1, 256, 0, stream>>>(tkidx, keepA, dstNK);
  pack_kernel<<<(Ev * CAPv) / 4, 256, 0, stream>>>(x, dstNK, BUF);

  // G1: per-expert convert w13 slice then SwiGLU GEMM
  for (int e = 0; e < Ev; ++e) {
    tconv_kernel<<<dim3(TH2v / 64, Dv / 64, 1), 256, 0, stream>>>(
        w13 + (size_t)e * Dv * TH2v, W13Be, Dv, TH2v);
    gemm128<1><<<dim3((CAPv / 128) * (Hv / 64), 1), 256, 0, stream>>>(
        BUF + (size_t)e * CAPv * Dv, BUF + (size_t)e * CAPv * Dv, Dv,
        W13Be, (void*)(ACT + (size_t)e * CAPv * Hv), nullptr,
        Dv, Dv, Dv, Hv, CAPv / 128, 0, 0, 0);
  }

  // G2: convert w2 (all experts), GEMM + scatter into SEL
  tconv_kernel<<<dim3(Dv / 64, Hv / 64, Ev), 256, 0, stream>>>(w2, W2B, Hv, Dv);
  gemm128<2><<<dim3((CAPv / 128) * (Dv / 128), Ev), 256, 0, stream>>>(
      ACT, ACT, Hv, W2B, (void*)SEL, dstNK,
      Hv, Hv, Hv, Dv, CAPv / 128, (size_t)CAPv * Hv, (size_t)Dv * Hv, 0);

  // small weight conversions
  tconv_kernel<<<dim3(16, 16, 1), 256, 0, stream>>>(msg_w, msgb, Dv, Dv);
  tconv_kernel<<<dim3(16, 16, 1), 256, 0, stream>>>(q_w, qb, Dv, Dv);
  tconv_kernel<<<dim3(16, 16, 1), 256, 0, stream>>>(k_w, kb, Dv, Dv);
  tconv_kernel<<<dim3(16, 16, 1), 256, 0, stream>>>(o_w, ob, Dv, Dv);
  tconv_kernel<<<dim3(32, 32, 1), 256, 0, stream>>>(upd_w1, upd1b, 2048, 2048);
  tconv_kernel<<<dim3(16, 32, 1), 256, 0, stream>>>(upd_w2, upd2b, 2048, Dv);

  // collaboration
  gemm128<0><<<dim3(64 * 8, 1), 256, 0, stream>>>(SEL, SEL, Dv, msgb, (void*)MBUF, nullptr,
      Dv, Dv, Dv, Dv, 64, 0, 0, 0);
  gemm128<0><<<dim3(64 * 8, 1), 256, 0, stream>>>(SEL, SEL, Dv, qb, (void*)QBUF, nullptr,
      Dv, Dv, Dv, Dv, 64, 0, 0, 0);
  gemm128<0><<<dim3(64 * 8, 1), 256, 0, stream>>>(MBUF, MBUF, Dv, kb, (void*)KKBUF, nullptr,
      Dv, Dv, Dv, Dv, 64, 0, 0, 0);
  scores_kernel<<<Nv / 4, 256, 0, stream>>>(QBUF, KKBUF, MBUF, keepA, CMSG);

  // update MLP: cat = [SEL | CMSG] via split-K A
  gemm128<3><<<dim3(64 * 16, 1), 256, 0, stream>>>(SEL, CMSG, Dv, upd1b, (void*)G1B, nullptr,
      2048, Dv, 2048, 2048, 64, 0, 0, 0);
  gemm128<0><<<dim3(64 * 8, 1), 256, 0, stream>>>(G1B, G1B, 2048, upd2b, (void*)UPDp, nullptr,
      2048, 2048, 2048, Dv, 64, 0, 0, 0);

  combine_kernel<<<Nv, 256, 0, stream>>>(SEL, UPDp, keepA, tkprob, FUSEDP);

  // output projection -> d_out (f32)
  gemm128<4><<<dim3(32 * 8, 1), 256, 0, stream>>>(FUSEDP, FUSEDP, Dv, ob, (void*)out, nullptr,
      Dv, Dv, Dv, Dv, 32, 0, 0, 0);

  (void)in_sizes; (void)n_in; (void)out_size; (void)ws_size;
}

// Round 2
// 661.612 us; speedup vs baseline: 1.1712x; 1.1712x over previous
//
#include <hip/hip_runtime.h>
#include <math.h>

#define Dv 1024
#define Ev 8
#define Hv 2816
#define Nv 4096
#define NKv 8192
#define CAPv 1280
#define TH2v 5632

typedef unsigned short u16;
typedef __attribute__((ext_vector_type(8))) short s16x8;
typedef __attribute__((ext_vector_type(4))) float f32x4;
typedef __attribute__((ext_vector_type(8))) u16 u16x8;
typedef __attribute__((ext_vector_type(4))) u16 u16x4;

typedef const __attribute__((address_space(1))) void* as1_cvp;
typedef __attribute__((address_space(3))) void* as3_vp;

__device__ __forceinline__ u16 f2bf(float f) {
  unsigned u = __float_as_uint(f);
  u += 0x7fffu + ((u >> 16) & 1u);
  return (u16)(u >> 16);
}
__device__ __forceinline__ float bf2f(u16 h) {
  return __uint_as_float(((unsigned)h) << 16);
}
__device__ __forceinline__ void gload16(const void* g, void* l) {
  __builtin_amdgcn_global_load_lds((as1_cvp)g, (as3_vp)l, 16, 0, 0);
}

// ---------------- router ----------------
__global__ __launch_bounds__(256) void router_kernel(
    const float* __restrict__ x, const float* __restrict__ gw,
    int* __restrict__ tkidx, float* __restrict__ tkprob,
    float* __restrict__ red, float* __restrict__ outIdx)
{
  __shared__ float lred[17];
  int tid = threadIdx.x;
  if (tid < 17) lred[tid] = 0.f;
  __syncthreads();
  int wv = tid >> 6, ln = tid & 63;
  int n = blockIdx.x * 4 + wv;
  float a[8] = {0.f,0.f,0.f,0.f,0.f,0.f,0.f,0.f};
  const float* xr = x + (size_t)n * Dv;
  #pragma unroll
  for (int it = 0; it < 16; ++it) {
    int d = ln + it * 64;
    float xs = xr[d];
    float4 g0 = *(const float4*)(gw + (size_t)d * 8);
    float4 g1 = *(const float4*)(gw + (size_t)d * 8 + 4);
    a[0] += xs * g0.x; a[1] += xs * g0.y; a[2] += xs * g0.z; a[3] += xs * g0.w;
    a[4] += xs * g1.x; a[5] += xs * g1.y; a[6] += xs * g1.z; a[7] += xs * g1.w;
  }
  #pragma unroll
  for (int off = 32; off >= 1; off >>= 1) {
    #pragma unroll
    for (int e = 0; e < 8; ++e) a[e] += __shfl_xor(a[e], off, 64);
  }
  int i1 = 0; float v1 = a[0];
  #pragma unroll
  for (int e = 1; e < 8; ++e) if (a[e] > v1) { v1 = a[e]; i1 = e; }
  int i2 = -1; float v2 = -1e30f;
  #pragma unroll
  for (int e = 0; e < 8; ++e) if (e != i1 && a[e] > v2) { v2 = a[e]; i2 = e; }
  float Z = 0.f;
  #pragma unroll
  for (int e = 0; e < 8; ++e) Z += expf(a[e] - v1);
  float zlse = v1 + logf(Z);
  float t = expf(v2 - v1);
  float p1 = 1.f / (1.f + t);
  float p2 = t * p1;
  if (ln == 0) {
    tkidx[2*n] = i1; tkidx[2*n+1] = i2;
    tkprob[2*n] = p1; tkprob[2*n+1] = p2;
    outIdx[2*n] = (float)i1; outIdx[2*n+1] = (float)i2;
    #pragma unroll
    for (int e = 0; e < 8; ++e) atomicAdd(&lred[e], expf(a[e] - v1) / Z);
    atomicAdd(&lred[8 + i1], 1.f);
    atomicAdd(&lred[16], zlse * zlse);
  }
  __syncthreads();
  if (tid < 17) atomicAdd(&red[tid], lred[tid]);
}

__global__ void aux_kernel(const float* __restrict__ red, float* __restrict__ outAux) {
  float bl = 0.f;
  for (int e = 0; e < 8; ++e) bl += (red[e] / (float)Nv) * (red[8 + e] / (float)Nv);
  bl *= (float)Ev;
  float zl = red[16] / (float)Nv;
  outAux[0] = 0.01f * bl + 0.001f * zl;
}

// ---------------- exact stable rank ----------------
__global__ __launch_bounds__(256) void rank_kernel(const int* __restrict__ tgt,
    int* __restrict__ keep, int* __restrict__ dstNK)
{
  __shared__ int hist[256][8];
  int t = threadIdx.x;
  int h[8] = {0,0,0,0,0,0,0,0};
  int base = t * 32;
  for (int j = 0; j < 32; ++j) h[tgt[base + j]]++;
  for (int e = 0; e < 8; ++e) hist[t][e] = h[e];
  __syncthreads();
  if (t < 8) {
    int run = 0;
    for (int tt = 0; tt < 256; ++tt) { int v = hist[tt][t]; hist[tt][t] = run; run += v; }
  }
  __syncthreads();
  for (int e = 0; e < 8; ++e) h[e] = hist[t][e];
  for (int j = 0; j < 32; ++j) {
    int i = base + j; int e = tgt[i]; int r = h[e]++;
    int kp = (r < CAPv) ? 1 : 0;
    keep[i] = kp;
    if (kp) dstNK[e * CAPv + r] = i;
  }
}

// ---------------- pack ----------------
__global__ __launch_bounds__(256) void pack_kernel(const float* __restrict__ x,
    const int* __restrict__ dstNK, u16* __restrict__ buf)
{
  int s = blockIdx.x * 4 + (threadIdx.x >> 6);
  int ln = threadIdx.x & 63;
  int i = dstNK[s];
  u16* dst = buf + (size_t)s * Dv;
  if (i >= 0) {
    const float* src = x + (size_t)(i >> 1) * Dv;
    #pragma unroll
    for (int j = 0; j < 2; ++j) {
      int d0 = ln * 16 + j * 8;
      float4 v0 = *(const float4*)(src + d0);
      float4 v1 = *(const float4*)(src + d0 + 4);
      u16x8 o;
      o[0]=f2bf(v0.x); o[1]=f2bf(v0.y); o[2]=f2bf(v0.z); o[3]=f2bf(v0.w);
      o[4]=f2bf(v1.x); o[5]=f2bf(v1.y); o[6]=f2bf(v1.z); o[7]=f2bf(v1.w);
      *(u16x8*)(dst + d0) = o;
    }
  } else {
    u16x8 z = {0,0,0,0,0,0,0,0};
    *(u16x8*)(dst + ln * 16) = z;
    *(u16x8*)(dst + ln * 16 + 8) = z;
  }
}

// ---------------- transpose + f32->bf16 ----------------
__global__ __launch_bounds__(256) void tconv_kernel(const float* __restrict__ in,
    u16* __restrict__ out, int R, int C)
{
  __shared__ u16 tile[64][68];
  size_t zoff = (size_t)blockIdx.z * (size_t)R * (size_t)C;
  in += zoff; out += zoff;
  int r0 = blockIdx.y * 64, c0 = blockIdx.x * 64;
  int t = threadIdx.x;
  int cc4 = (t & 15) * 4;
  #pragma unroll
  for (int p = 0; p < 4; ++p) {
    int r = (t >> 4) + p * 16;
    float4 v = *(const float4*)(in + (size_t)(r0 + r) * C + c0 + cc4);
    u16x4 b; b[0]=f2bf(v.x); b[1]=f2bf(v.y); b[2]=f2bf(v.z); b[3]=f2bf(v.w);
    *(u16x4*)(&tile[r][cc4]) = b;
  }
  __syncthreads();
  int rr4 = (t & 15) * 4;
  #pragma unroll
  for (int p = 0; p < 4; ++p) {
    int c = (t >> 4) + p * 16;
    u16x4 o; o[0]=tile[rr4][c]; o[1]=tile[rr4+1][c]; o[2]=tile[rr4+2][c]; o[3]=tile[rr4+3][c];
    *(u16x4*)(out + (size_t)(c0 + c) * R + r0 + rr4) = o;
  }
}

// ================= 256x256 8-wave phase-split GEMM, NT, BK=64 =================
// MODE 0: store bf16  1: SwiGLU (per-wave gate/up pairing)  2: scatter via dst
// MODE 3: gelu + split-K A (A for k<splitK, A2 after)
template<int MODE>
__global__ __launch_bounds__(512, 2) void gemm256(
    const u16* __restrict__ A, const u16* __restrict__ A2, int splitK,
    const u16* __restrict__ B, void* __restrict__ C,
    const int* __restrict__ dst,
    int Ksz, int lda, int ldb, int ldc, int ntm,
    size_t sA, size_t sB, size_t sC)
{
  __shared__ char smem[131072];  // A dbuf [0,64K), B dbuf [64K,128K)
  int e = blockIdx.y;
  int nwgx = gridDim.x;
  int bid0 = blockIdx.x;
  // bijective XCD swizzle (m204)
  int q = nwgx >> 3, r = nwgx & 7;
  int xcd = bid0 & 7, lo = bid0 >> 3;
  int bid = (xcd < r ? xcd * (q + 1) : r * (q + 1) + (xcd - r) * q) + lo;
  int tm = bid % ntm, tn = bid / ntm;
  const u16* Ae  = A  + (size_t)e * sA;
  const u16* A2e = A2 + (size_t)e * sA;
  const u16* Be  = B  + (size_t)e * sB;
  long long bdelta = (const char*)A2e - (const char*)Ae;
  int tid = threadIdx.x, wv = tid >> 6, ln = tid & 63;
  int wr = wv >> 2, wc = wv & 3;
  int lnl = ln & 15, lnh = ln >> 4;

  // staging source pointers (pre-swizzled global so linear gload_lds lands swizzled)
  const char* aP[4]; const char* bP[4];
  int colsw = ((tid & 7) << 4) ^ (((tid >> 3) & 7) << 4);
  #pragma unroll
  for (int i = 0; i < 4; ++i) {
    int row = i * 64 + (tid >> 3);
    aP[i] = (const char*)(Ae + (size_t)(tm * 256 + row) * lda) + colsw;
    int brow;
    if (MODE == 1) {
      int s = row & 63, wcl = row >> 6;
      brow = (s < 32) ? (tn * 128 + wcl * 32 + s) : (Hv + tn * 128 + wcl * 32 + (s - 32));
    } else {
      brow = tn * 256 + row;
    }
    bP[i] = (const char*)(Be + (size_t)brow * ldb) + colsw;
  }

  // fragment LDS byte offsets
  int arow0 = wr * 128 + lnl;
  int brow0 = wc * 64 + lnl;
  int ksw0 = ((lnh << 4)) ^ ((ln & 7) << 4);
  int ksw1 = (64 + (lnh << 4)) ^ ((ln & 7) << 4);

  auto stage = [&](int t1, int bsel) {
    int k0 = t1 << 6;
    long long kbA;
    if (MODE == 3 && k0 >= splitK) kbA = bdelta + (long long)(k0 - splitK) * 2;
    else kbA = (long long)k0 * 2;
    long long kbB = (long long)k0 * 2;
    char* ldsA = smem + bsel * 32768 + (wv << 10);
    char* ldsB = smem + 65536 + bsel * 32768 + (wv << 10);
    #pragma unroll
    for (int i = 0; i < 4; ++i) {
      gload16(aP[i] + kbA, ldsA + i * 8192);
      gload16(bP[i] + kbB, ldsB + i * 8192);
    }
  };

  f32x4 acc[8][4];
  #pragma unroll
  for (int m = 0; m < 8; ++m)
    #pragma unroll
    for (int n = 0; n < 4; ++n) acc[m][n] = (f32x4){0.f, 0.f, 0.f, 0.f};

  int nt = Ksz >> 6;
  stage(0, 0);
  asm volatile("s_waitcnt vmcnt(0)" ::: "memory");
  __builtin_amdgcn_s_barrier();

  for (int t = 0; t < nt; ++t) {
    int cur = t & 1;
    const char* sa = smem + cur * 32768;
    const char* sb = smem + 65536 + cur * 32768;
    if (t + 1 < nt) stage(t + 1, cur ^ 1);   // 8 gloads early: ~4 phases of cover
    s16x8 bfr[4][2];
    #pragma unroll
    for (int n = 0; n < 4; ++n) {
      bfr[n][0] = *(const s16x8*)(sb + (brow0 + n * 16) * 128 + ksw0);
      bfr[n][1] = *(const s16x8*)(sb + (brow0 + n * 16) * 128 + ksw1);
    }
    #pragma unroll
    for (int p = 0; p < 4; ++p) {
      s16x8 af0_0 = *(const s16x8*)(sa + (arow0 + (p * 2 + 0) * 16) * 128 + ksw0);
      s16x8 af0_1 = *(const s16x8*)(sa + (arow0 + (p * 2 + 0) * 16) * 128 + ksw1);
      s16x8 af1_0 = *(const s16x8*)(sa + (arow0 + (p * 2 + 1) * 16) * 128 + ksw0);
      s16x8 af1_1 = *(const s16x8*)(sa + (arow0 + (p * 2 + 1) * 16) * 128 + ksw1);
      __builtin_amdgcn_s_barrier();
      __builtin_amdgcn_s_setprio(1);
      #pragma unroll
      for (int n = 0; n < 4; ++n) {
        acc[p*2+0][n] = __builtin_amdgcn_mfma_f32_16x16x32_bf16(af0_0, bfr[n][0], acc[p*2+0][n], 0, 0, 0);
        acc[p*2+0][n] = __builtin_amdgcn_mfma_f32_16x16x32_bf16(af0_1, bfr[n][1], acc[p*2+0][n], 0, 0, 0);
        acc[p*2+1][n] = __builtin_amdgcn_mfma_f32_16x16x32_bf16(af1_0, bfr[n][0], acc[p*2+1][n], 0, 0, 0);
        acc[p*2+1][n] = __builtin_amdgcn_mfma_f32_16x16x32_bf16(af1_1, bfr[n][1], acc[p*2+1][n], 0, 0, 0);
      }
      __builtin_amdgcn_s_setprio(0);
      __builtin_amdgcn_s_barrier();
    }
    asm volatile("s_waitcnt vmcnt(0)" ::: "memory");
    __builtin_amdgcn_s_barrier();
  }

  int rb = tm * 256 + wr * 128 + (lnh << 2);
  if (MODE == 0) {
    u16* Cp = (u16*)C;
    #pragma unroll
    for (int m = 0; m < 8; ++m)
      #pragma unroll
      for (int n = 0; n < 4; ++n) {
        int col = tn * 256 + wc * 64 + n * 16 + lnl;
        #pragma unroll
        for (int v = 0; v < 4; ++v)
          Cp[(size_t)(rb + m * 16 + v) * ldc + col] = f2bf(acc[m][n][v]);
      }
  } else if (MODE == 1) {
    u16* Cp = (u16*)C + (size_t)e * sC;
    #pragma unroll
    for (int m = 0; m < 8; ++m)
      #pragma unroll
      for (int n = 0; n < 2; ++n) {
        int col = tn * 128 + wc * 32 + n * 16 + lnl;
        #pragma unroll
        for (int v = 0; v < 4; ++v) {
          float g = acc[m][n][v];
          float u = acc[m][n + 2][v];
          float sg = g / (1.f + __expf(-g));
          Cp[(size_t)(rb + m * 16 + v) * ldc + col] = f2bf(sg * u);
        }
      }
  } else if (MODE == 2) {
    u16* Cp = (u16*)C;
    #pragma unroll
    for (int m = 0; m < 8; ++m)
      #pragma unroll
      for (int v = 0; v < 4; ++v) {
        int gr = rb + m * 16 + v;
        int i = dst[e * CAPv + gr];
        if (i >= 0) {
          #pragma unroll
          for (int n = 0; n < 4; ++n)
            Cp[(size_t)i * Dv + tn * 256 + wc * 64 + n * 16 + lnl] = f2bf(acc[m][n][v]);
        }
      }
  } else {
    u16* Cp = (u16*)C;
    #pragma unroll
    for (int m = 0; m < 8; ++m)
      #pragma unroll
      for (int n = 0; n < 4; ++n) {
        int col = tn * 256 + wc * 64 + n * 16 + lnl;
        #pragma unroll
        for (int v = 0; v < 4; ++v) {
          float xg = acc[m][n][v];
          float gl = 0.5f * xg * (1.f + erff(xg * 0.70710678118654752f));
          Cp[(size_t)(rb + m * 16 + v) * ldc + col] = f2bf(gl);
        }
      }
  }
}

// ---------------- 128x128 GEMM (kept for small final projection) ----------------
template<int MODE>
__global__ __launch_bounds__(256) void gemm128(
    const u16* __restrict__ A, const u16* __restrict__ A2, int splitK,
    const u16* __restrict__ B, void* __restrict__ C,
    const int* __restrict__ dst,
    int Ksz, int lda, int ldb, int ldc, int ntm,
    size_t sA, size_t sB, size_t sC)
{
  __shared__ char smem[32768];
  int e = blockIdx.y;
  int bid = blockIdx.x;
  int tm = bid % ntm, tn = bid / ntm;
  const u16* Ae  = A  + (size_t)e * sA;
  const u16* Be  = B  + (size_t)e * sB;
  int tid = threadIdx.x, wv = tid >> 6, ln = tid & 63;

  const char* aP[4]; const char* bP[4];
  unsigned aL[4], bL[4];
  #pragma unroll
  for (int r = 0; r < 4; ++r) {
    int lb = r * 4096 + tid * 16;
    int row = lb >> 7;
    int colb = (lb & 127) ^ ((row & 7) << 4);
    aP[r] = (const char*)(Ae + (size_t)(tm * 128 + row) * lda) + colb;
    bP[r] = (const char*)(Be + (size_t)(tn * 128 + row) * ldb) + colb;
    aL[r] = r * 4096 + wv * 1024;
    bL[r] = 16384 + r * 4096 + wv * 1024;
  }

  f32x4 acc[2][8];
  #pragma unroll
  for (int m = 0; m < 2; ++m)
    #pragma unroll
    for (int n = 0; n < 8; ++n) acc[m][n] = (f32x4){0.f, 0.f, 0.f, 0.f};

  for (int k0 = 0; k0 < Ksz; k0 += 64) {
    size_t kb = (size_t)k0 * 2;
    #pragma unroll
    for (int r = 0; r < 4; ++r) gload16(aP[r] + kb, smem + aL[r]);
    #pragma unroll
    for (int r = 0; r < 4; ++r) gload16(bP[r] + kb, smem + bL[r]);
    __syncthreads();
    #pragma unroll
    for (int ks = 0; ks < 2; ++ks) {
      int kbyte = ks * 64 + ((ln >> 4) << 4);
      s16x8 av[2];
      #pragma unroll
      for (int m = 0; m < 2; ++m) {
        int row = wv * 32 + m * 16 + (ln & 15);
        av[m] = *(const s16x8*)(smem + (row << 7) + (kbyte ^ ((row & 7) << 4)));
      }
      #pragma unroll
      for (int n = 0; n < 8; ++n) {
        int row = n * 16 + (ln & 15);
        s16x8 bv = *(const s16x8*)(smem + 16384 + (row << 7) + (kbyte ^ ((row & 7) << 4)));
        acc[0][n] = __builtin_amdgcn_mfma_f32_16x16x32_bf16(av[0], bv, acc[0][n], 0, 0, 0);
        acc[1][n] = __builtin_amdgcn_mfma_f32_16x16x32_bf16(av[1], bv, acc[1][n], 0, 0, 0);
      }
    }
    __syncthreads();
  }

  int rbase = tm * 128 + wv * 32 + ((ln >> 4) << 2);
  int cb = (ln & 15);
  float* Cp = (float*)C;
  #pragma unroll
  for (int m = 0; m < 2; ++m)
    #pragma unroll
    for (int n = 0; n < 8; ++n)
      #pragma unroll
      for (int v = 0; v < 4; ++v)
        Cp[(size_t)(rbase + m * 16 + v) * ldc + tn * 128 + n * 16 + cb] = acc[m][n][v];
  (void)A2; (void)splitK; (void)dst; (void)sC;
}

// ---------------- per-token scores + masked softmax + Cmsg ----------------
__global__ __launch_bounds__(256) void scores_kernel(
    const u16* __restrict__ MQ, const u16* __restrict__ KK,
    const int* __restrict__ keep, u16* __restrict__ Cmsg)
{
  int wv = threadIdx.x >> 6, ln = threadIdx.x & 63;
  int n = blockIdx.x * 4 + wv;
  const u16* m0 = MQ + (size_t)(2 * n) * 2048;
  const u16* m1 = MQ + (size_t)(2 * n + 1) * 2048;
  const u16* q0 = m0 + 1024;
  const u16* q1 = m1 + 1024;
  const u16* k0p = KK + (size_t)(2 * n) * 1024;
  const u16* k1p = KK + (size_t)(2 * n + 1) * 1024;
  float s00 = 0, s01 = 0, s10 = 0, s11 = 0;
  #pragma unroll
  for (int j = 0; j < 2; ++j) {
    int d0 = ln * 16 + j * 8;
    u16x8 a0 = *(const u16x8*)(q0 + d0);
    u16x8 a1 = *(const u16x8*)(q1 + d0);
    u16x8 b0 = *(const u16x8*)(k0p + d0);
    u16x8 b1 = *(const u16x8*)(k1p + d0);
    #pragma unroll
    for (int t = 0; t < 8; ++t) {
      float fa0 = bf2f(a0[t]), fa1 = bf2f(a1[t]);
      float fb0 = bf2f(b0[t]), fb1 = bf2f(b1[t]);
      s00 += fa0 * fb0; s01 += fa0 * fb1; s10 += fa1 * fb0; s11 += fa1 * fb1;
    }
  }
  #pragma unroll
  for (int off = 32; off >= 1; off >>= 1) {
    s00 += __shfl_xor(s00, off, 64);
    s01 += __shfl_xor(s01, off, 64);
    s10 += __shfl_xor(s10, off, 64);
    s11 += __shfl_xor(s11, off, 64);
  }
  const float inv = 0.03125f;
  int kp0 = keep[2 * n], kp1 = keep[2 * n + 1];
  float A00, A01, A10, A11;
  {
    float v0 = kp0 ? s00 * inv : -1e9f;
    float v1 = (kp0 && kp1) ? s01 * inv : -1e9f;
    float mx = fmaxf(v0, v1);
    float e0 = expf(v0 - mx), e1 = expf(v1 - mx);
    float den = e0 + e1;
    float a0 = kp0 ? e0 / den : 0.f;
    float a1 = (kp0 && kp1) ? e1 / den : 0.f;
    float s = fmaxf(a0 + a1, 1e-12f);
    A00 = a0 / s; A01 = a1 / s;
  }
  {
    float v0 = (kp1 && kp0) ? s10 * inv : -1e9f;
    float v1 = kp1 ? s11 * inv : -1e9f;
    float mx = fmaxf(v0, v1);
    float e0 = expf(v0 - mx), e1 = expf(v1 - mx);
    float den = e0 + e1;
    float a0 = (kp1 && kp0) ? e0 / den : 0.f;
    float a1 = kp1 ? e1 / den : 0.f;
    float s = fmaxf(a0 + a1, 1e-12f);
    A10 = a0 / s; A11 = a1 / s;
  }
  u16* c0 = Cmsg + (size_t)(2 * n) * 1024;
  u16* c1 = Cmsg + (size_t)(2 * n + 1) * 1024;
  #pragma unroll
  for (int j = 0; j < 2; ++j) {
    int d0 = ln * 16 + j * 8;
    u16x8 x0 = *(const u16x8*)(m0 + d0);
    u16x8 x1 = *(const u16x8*)(m1 + d0);
    u16x8 o0, o1;
    #pragma unroll
    for (int t = 0; t < 8; ++t) {
      float f0 = bf2f(x0[t]), f1 = bf2f(x1[t]);
      o0[t] = f2bf(A00 * f0 + A01 * f1);
      o1[t] = f2bf(A10 * f0 + A11 * f1);
    }
    *(u16x8*)(c0 + d0) = o0;
    *(u16x8*)(c1 + d0) = o1;
  }
}

// ---------------- combine ----------------
__global__ __launch_bounds__(256) void combine_kernel(
    const u16* __restrict__ sel, const u16* __restrict__ upd,
    const int* __restrict__ keep, const float* __restrict__ tkprob,
    u16* __restrict__ fusedp)
{
  int n = blockIdx.x;
  int t = threadIdx.x;
  float kp0 = keep[2 * n] ? 1.f : 0.f, kp1 = keep[2 * n + 1] ? 1.f : 0.f;
  float p0 = tkprob[2 * n] * kp0, p1 = tkprob[2 * n + 1] * kp1;
  float s = fmaxf(p0 + p1, 1e-12f);
  float w0 = p0 / s, w1 = p1 / s;
  int d0 = t * 4;
  u16x4 s0 = *(const u16x4*)(sel + (size_t)(2 * n) * Dv + d0);
  u16x4 s1 = *(const u16x4*)(sel + (size_t)(2 * n + 1) * Dv + d0);
  u16x4 u0 = *(const u16x4*)(upd + (size_t)(2 * n) * Dv + d0);
  u16x4 u1 = *(const u16x4*)(upd + (size_t)(2 * n + 1) * Dv + d0);
  u16x4 o;
  #pragma unroll
  for (int j = 0; j < 4; ++j) {
    float r0 = (bf2f(s0[j]) + bf2f(u0[j])) * kp0;
    float r1 = (bf2f(s1[j]) + bf2f(u1[j])) * kp1;
    o[j] = f2bf(w0 * r0 + w1 * r1);
  }
  *(u16x4*)(fusedp + (size_t)n * Dv + d0) = o;
}

extern "C" void kernel_launch(void* const* d_in, const int* in_sizes, int n_in,
                              void* d_out, int out_size, void* d_ws, size_t ws_size,
                              hipStream_t stream) {
  const float* x      = (const float*)d_in[0];
  const float* gate_w = (const float*)d_in[1];
  const float* w13    = (const float*)d_in[2];
  const float* w2     = (const float*)d_in[3];
  const float* msg_w  = (const float*)d_in[4];
  const float* q_w    = (const float*)d_in[5];
  const float* k_w    = (const float*)d_in[6];
  const float* upd_w1 = (const float*)d_in[7];
  const float* upd_w2 = (const float*)d_in[8];
  const float* o_w    = (const float*)d_in[9];
  float* out = (float*)d_out;
  float* outAux = out + (size_t)Nv * Dv;
  float* outIdx = outAux + 1;

  char* ws = (char*)d_ws;
  const size_t MBc = 1ull << 20;
  // control block [0,1MiB)
  int*   tkidx  = (int*)(ws + 0);
  float* tkprob = (float*)(ws + 32768);
  int*   keepA  = (int*)(ws + 65536);
  int*   dstNK  = (int*)(ws + 98304);
  float* red    = (float*)(ws + 143360);
  // phase A (dispatch + experts):
  u16* BUF   = (u16*)(ws + 1 * MBc);    // 20 MiB  [1,21)
  u16* ACT   = (u16*)(ws + 21 * MBc);   // 55 MiB  [21,76)
  u16* W13B  = (u16*)(ws + 76 * MBc);   // 88 MiB  [76,164)  dead after G1
  u16* W2B   = (u16*)(ws + 76 * MBc);   // 44 MiB  [76,120)  converted after G1
  u16* SEL   = (u16*)(ws + 120 * MBc);  // 16 MiB  [120,136) lives to combine
  u16* MSGQB = (u16*)(ws + 136 * MBc);  //  4 MiB  [136,140)
  u16* KB    = (u16*)(ws + 140 * MBc);  //  2 MiB
  u16* OB    = (u16*)(ws + 142 * MBc);  //  2 MiB
  u16* UPD1B = (u16*)(ws + 144 * MBc);  //  8 MiB
  u16* UPD2B = (u16*)(ws + 152 * MBc);  //  4 MiB
  // phase B (collab/update, overlays dead BUF/ACT/W2B):
  u16* MQ    = (u16*)(ws + 1 * MBc);    // 32 MiB  [1,33)
  u16* KKb   = (u16*)(ws + 33 * MBc);   // 16 MiB  [33,49)
  u16* CMSG  = (u16*)(ws + 49 * MBc);   // 16 MiB  [49,65)
  u16* G1B   = (u16*)(ws + 65 * MBc);   // 32 MiB  [65,97)
  u16* UPD   = (u16*)(ws + 97 * MBc);   // 16 MiB  [97,113)
  u16* FUSEDP= (u16*)(ws + 1 * MBc);    //  8 MiB  (MQ dead by then)

  hipMemsetAsync(red, 0, 68, stream);
  hipMemsetAsync(dstNK, 0xFF, Ev * CAPv * 4, stream);

  router_kernel<<<Nv / 4, 256, 0, stream>>>(x, gate_w, tkidx, tkprob, red, outIdx);
  aux_kernel<<<1, 1, 0, stream>>>(red, outAux);
  rank_kernel<<<1, 256, 0, stream>>>(tkidx, keepA, dstNK);
  pack_kernel<<<(Ev * CAPv) / 4, 256, 0, stream>>>(x, dstNK, BUF);

  // G1: convert all w13, one batched SwiGLU GEMM (880 blocks)
  tconv_kernel<<<dim3(TH2v / 64, Dv / 64, Ev), 256, 0, stream>>>(w13, W13B, Dv, TH2v);
  gemm256<1><<<dim3((CAPv / 256) * (Hv / 128), Ev), 512, 0, stream>>>(
      BUF, BUF, 1 << 30, W13B, (void*)ACT, nullptr,
      Dv, Dv, Dv, Hv, CAPv / 256, (size_t)CAPv * Dv, (size_t)TH2v * Dv, (size_t)CAPv * Hv);

  // after G1: W13B dead -> convert w2 + small weights, zero SEL
  hipMemsetAsync(SEL, 0, (size_t)NKv * Dv * 2, stream);
  tconv_kernel<<<dim3(Dv / 64, Hv / 64, Ev), 256, 0, stream>>>(w2, W2B, Hv, Dv);
  tconv_kernel<<<dim3(16, 16, 1), 256, 0, stream>>>(msg_w, MSGQB, Dv, Dv);
  tconv_kernel<<<dim3(16, 16, 1), 256, 0, stream>>>(q_w, MSGQB + (size_t)Dv * Dv, Dv, Dv);
  tconv_kernel<<<dim3(16, 16, 1), 256, 0, stream>>>(k_w, KB, Dv, Dv);
  tconv_kernel<<<dim3(16, 16, 1), 256, 0, stream>>>(o_w, OB, Dv, Dv);
  tconv_kernel<<<dim3(32, 32, 1), 256, 0, stream>>>(upd_w1, UPD1B, 2048, 2048);
  tconv_kernel<<<dim3(16, 32, 1), 256, 0, stream>>>(upd_w2, UPD2B, 2048, Dv);

  // G2: GEMM + scatter into SEL (160 blocks)
  gemm256<2><<<dim3((CAPv / 256) * (Dv / 256), Ev), 512, 0, stream>>>(
      ACT, ACT, 1 << 30, W2B, (void*)SEL, dstNK,
      Hv, Hv, Hv, Dv, CAPv / 256, (size_t)CAPv * Hv, (size_t)Dv * Hv, 0);

  // collaboration: fused [M|Q] GEMM, then Kk GEMM, then scores
  gemm256<0><<<dim3(32 * 8, 1), 512, 0, stream>>>(SEL, SEL, 1 << 30, MSGQB, (void*)MQ, nullptr,
      Dv, Dv, Dv, 2048, 32, 0, 0, 0);
  gemm256<0><<<dim3(32 * 4, 1), 512, 0, stream>>>(MQ, MQ, 1 << 30, KB, (void*)KKb, nullptr,
      Dv, 2048, Dv, Dv, 32, 0, 0, 0);
  scores_kernel<<<Nv / 4, 256, 0, stream>>>(MQ, KKb, keepA, CMSG);

  // update MLP: cat = [SEL | CMSG] via split-K A, gelu fused
  gemm256<3><<<dim3(32 * 8, 1), 512, 0, stream>>>(SEL, CMSG, Dv, UPD1B, (void*)G1B, nullptr,
      2048, Dv, 2048, 2048, 32, 0, 0, 0);
  gemm256<0><<<dim3(32 * 4, 1), 512, 0, stream>>>(G1B, G1B, 1 << 30, UPD2B, (void*)UPD, nullptr,
      2048, 2048, 2048, Dv, 32, 0, 0, 0);

  combine_kernel<<<Nv, 256, 0, stream>>>(SEL, UPD, keepA, tkprob, FUSEDP);

  // output projection -> d_out (f32)
  gemm128<4><<<dim3(32 * 8, 1), 256, 0, stream>>>(FUSEDP, FUSEDP, Dv, OB, (void*)out, nullptr,
      Dv, Dv, Dv, Dv, 32, 0, 0, 0);

  (void)in_sizes; (void)n_in; (void)out_size; (void)ws_size;
}

// Round 3
// 624.410 us; speedup vs baseline: 1.2410x; 1.0596x over previous
//
#include <hip/hip_runtime.h>
#include <math.h>

#define Dv 1024
#define Ev 8
#define Hv 2816
#define Nv 4096
#define NKv 8192
#define CAPv 1280
#define TH2v 5632

typedef unsigned short u16;
typedef __attribute__((ext_vector_type(8))) short s16x8;
typedef __attribute__((ext_vector_type(4))) float f32x4;
typedef __attribute__((ext_vector_type(8))) u16 u16x8;
typedef __attribute__((ext_vector_type(4))) u16 u16x4;

typedef const __attribute__((address_space(1))) void* as1_cvp;
typedef __attribute__((address_space(3))) void* as3_vp;

__device__ __forceinline__ u16 f2bf(float f) {
  unsigned u = __float_as_uint(f);
  u += 0x7fffu + ((u >> 16) & 1u);
  return (u16)(u >> 16);
}
__device__ __forceinline__ float bf2f(u16 h) {
  return __uint_as_float(((unsigned)h) << 16);
}
__device__ __forceinline__ void gload16(const void* g, void* l) {
  __builtin_amdgcn_global_load_lds((as1_cvp)g, (as3_vp)l, 16, 0, 0);
}

// ---------------- router ----------------
__global__ __launch_bounds__(256) void router_kernel(
    const float* __restrict__ x, const float* __restrict__ gw,
    int* __restrict__ tkidx, float* __restrict__ tkprob,
    float* __restrict__ red, float* __restrict__ outIdx)
{
  __shared__ float lred[17];
  int tid = threadIdx.x;
  if (tid < 17) lred[tid] = 0.f;
  __syncthreads();
  int wv = tid >> 6, ln = tid & 63;
  int n = blockIdx.x * 4 + wv;
  float a[8] = {0.f,0.f,0.f,0.f,0.f,0.f,0.f,0.f};
  const float* xr = x + (size_t)n * Dv;
  #pragma unroll
  for (int it = 0; it < 16; ++it) {
    int d = ln + it * 64;
    float xs = xr[d];
    float4 g0 = *(const float4*)(gw + (size_t)d * 8);
    float4 g1 = *(const float4*)(gw + (size_t)d * 8 + 4);
    a[0] += xs * g0.x; a[1] += xs * g0.y; a[2] += xs * g0.z; a[3] += xs * g0.w;
    a[4] += xs * g1.x; a[5] += xs * g1.y; a[6] += xs * g1.z; a[7] += xs * g1.w;
  }
  #pragma unroll
  for (int off = 32; off >= 1; off >>= 1) {
    #pragma unroll
    for (int e = 0; e < 8; ++e) a[e] += __shfl_xor(a[e], off, 64);
  }
  int i1 = 0; float v1 = a[0];
  #pragma unroll
  for (int e = 1; e < 8; ++e) if (a[e] > v1) { v1 = a[e]; i1 = e; }
  int i2 = -1; float v2 = -1e30f;
  #pragma unroll
  for (int e = 0; e < 8; ++e) if (e != i1 && a[e] > v2) { v2 = a[e]; i2 = e; }
  float Z = 0.f;
  #pragma unroll
  for (int e = 0; e < 8; ++e) Z += expf(a[e] - v1);
  float zlse = v1 + logf(Z);
  float t = expf(v2 - v1);
  float p1 = 1.f / (1.f + t);
  float p2 = t * p1;
  if (ln == 0) {
    tkidx[2*n] = i1; tkidx[2*n+1] = i2;
    tkprob[2*n] = p1; tkprob[2*n+1] = p2;
    outIdx[2*n] = (float)i1; outIdx[2*n+1] = (float)i2;
    #pragma unroll
    for (int e = 0; e < 8; ++e) atomicAdd(&lred[e], expf(a[e] - v1) / Z);
    atomicAdd(&lred[8 + i1], 1.f);
    atomicAdd(&lred[16], zlse * zlse);
  }
  __syncthreads();
  if (tid < 17) atomicAdd(&red[tid], lred[tid]);
}

__global__ void aux_kernel(const float* __restrict__ red, float* __restrict__ outAux) {
  float bl = 0.f;
  for (int e = 0; e < 8; ++e) bl += (red[e] / (float)Nv) * (red[8 + e] / (float)Nv);
  bl *= (float)Ev;
  float zl = red[16] / (float)Nv;
  outAux[0] = 0.01f * bl + 0.001f * zl;
}

// ---------------- exact stable rank ----------------
__global__ __launch_bounds__(256) void rank_kernel(const int* __restrict__ tgt,
    int* __restrict__ keep, int* __restrict__ dstNK)
{
  __shared__ int hist[256][8];
  int t = threadIdx.x;
  int h[8] = {0,0,0,0,0,0,0,0};
  int base = t * 32;
  for (int j = 0; j < 32; ++j) h[tgt[base + j]]++;
  for (int e = 0; e < 8; ++e) hist[t][e] = h[e];
  __syncthreads();
  if (t < 8) {
    int run = 0;
    for (int tt = 0; tt < 256; ++tt) { int v = hist[tt][t]; hist[tt][t] = run; run += v; }
  }
  __syncthreads();
  for (int e = 0; e < 8; ++e) h[e] = hist[t][e];
  for (int j = 0; j < 32; ++j) {
    int i = base + j; int e = tgt[i]; int r = h[e]++;
    int kp = (r < CAPv) ? 1 : 0;
    keep[i] = kp;
    if (kp) dstNK[e * CAPv + r] = i;
  }
}

// ---------------- pack ----------------
__global__ __launch_bounds__(256) void pack_kernel(const float* __restrict__ x,
    const int* __restrict__ dstNK, u16* __restrict__ buf)
{
  int s = blockIdx.x * 4 + (threadIdx.x >> 6);
  int ln = threadIdx.x & 63;
  int i = dstNK[s];
  u16* dst = buf + (size_t)s * Dv;
  if (i >= 0) {
    const float* src = x + (size_t)(i >> 1) * Dv;
    #pragma unroll
    for (int j = 0; j < 2; ++j) {
      int d0 = ln * 16 + j * 8;
      float4 v0 = *(const float4*)(src + d0);
      float4 v1 = *(const float4*)(src + d0 + 4);
      u16x8 o;
      o[0]=f2bf(v0.x); o[1]=f2bf(v0.y); o[2]=f2bf(v0.z); o[3]=f2bf(v0.w);
      o[4]=f2bf(v1.x); o[5]=f2bf(v1.y); o[6]=f2bf(v1.z); o[7]=f2bf(v1.w);
      *(u16x8*)(dst + d0) = o;
    }
  } else {
    u16x8 z = {0,0,0,0,0,0,0,0};
    *(u16x8*)(dst + ln * 16) = z;
    *(u16x8*)(dst + ln * 16 + 8) = z;
  }
}

// ---------------- transpose + f32->bf16 ----------------
__global__ __launch_bounds__(256) void tconv_kernel(const float* __restrict__ in,
    u16* __restrict__ out, int R, int C)
{
  __shared__ u16 tile[64][68];
  size_t zoff = (size_t)blockIdx.z * (size_t)R * (size_t)C;
  in += zoff; out += zoff;
  int r0 = blockIdx.y * 64, c0 = blockIdx.x * 64;
  int t = threadIdx.x;
  int cc4 = (t & 15) * 4;
  #pragma unroll
  for (int p = 0; p < 4; ++p) {
    int r = (t >> 4) + p * 16;
    float4 v = *(const float4*)(in + (size_t)(r0 + r) * C + c0 + cc4);
    u16x4 b; b[0]=f2bf(v.x); b[1]=f2bf(v.y); b[2]=f2bf(v.z); b[3]=f2bf(v.w);
    *(u16x4*)(&tile[r][cc4]) = b;
  }
  __syncthreads();
  int rr4 = (t & 15) * 4;
  #pragma unroll
  for (int p = 0; p < 4; ++p) {
    int c = (t >> 4) + p * 16;
    u16x4 o; o[0]=tile[rr4][c]; o[1]=tile[rr4+1][c]; o[2]=tile[rr4+2][c]; o[3]=tile[rr4+3][c];
    *(u16x4*)(out + (size_t)(c0 + c) * R + r0 + rr4) = o;
  }
}

// ================= 256x256 8-wave GEMM, counted-vmcnt pipeline (T3+T4+T5) ==========
// MODE 0: store bf16  1: SwiGLU  2: scatter via dst  3: gelu + split-K A
template<int MODE>
__global__ __launch_bounds__(512, 2) void gemm256(
    const u16* __restrict__ A, const u16* __restrict__ A2, int splitK,
    const u16* __restrict__ B, void* __restrict__ C,
    const int* __restrict__ dst,
    int Ksz, int lda, int ldb, int ldc, int ntm,
    size_t sA, size_t sB, size_t sC)
{
  __shared__ char smem[131072];  // A dbuf [0,64K), B dbuf [64K,128K)
  int e = blockIdx.y;
  int nwgx = gridDim.x;
  int bid0 = blockIdx.x;
  int q = nwgx >> 3, r = nwgx & 7;
  int xcd = bid0 & 7, lo = bid0 >> 3;
  int bid = (xcd < r ? xcd * (q + 1) : r * (q + 1) + (xcd - r) * q) + lo;
  int tm = bid % ntm, tn = bid / ntm;
  const u16* Ae  = A  + (size_t)e * sA;
  const u16* A2e = A2 + (size_t)e * sA;
  const u16* Be  = B  + (size_t)e * sB;
  long long bdelta = (const char*)A2e - (const char*)Ae;
  int tid = threadIdx.x, wv = tid >> 6, ln = tid & 63;
  int wr = wv >> 2, wc = wv & 3;
  int lnl = ln & 15, lnh = ln >> 4;

  // staging source pointers (pre-swizzled global; linear gload_lds dest)
  const char* aP[4]; const char* bP[4];
  int colsw = ((tid & 7) << 4) ^ (((tid >> 3) & 7) << 4);
  #pragma unroll
  for (int i = 0; i < 4; ++i) {
    int row = i * 64 + (tid >> 3);
    aP[i] = (const char*)(Ae + (size_t)(tm * 256 + row) * lda) + colsw;
    int brow;
    if (MODE == 1) {
      int s = row & 63, wcl = row >> 6;
      brow = (s < 32) ? (tn * 128 + wcl * 32 + s) : (Hv + tn * 128 + wcl * 32 + (s - 32));
    } else {
      brow = tn * 256 + row;
    }
    bP[i] = (const char*)(Be + (size_t)brow * ldb) + colsw;
  }

  // fragment LDS byte offsets
  int arow0 = wr * 128 + lnl;
  int brow0 = wc * 64 + lnl;
  int ksw0 = ((lnh << 4)) ^ ((ln & 7) << 4);
  int ksw1 = (64 + (lnh << 4)) ^ ((ln & 7) << 4);

  auto issueA = [&](int t1, int bsel, int band) {
    int k0 = t1 << 6;
    long long kbA;
    if (MODE == 3 && k0 >= splitK) kbA = bdelta + (long long)(k0 - splitK) * 2;
    else kbA = (long long)k0 * 2;
    gload16(aP[band] + kbA, smem + bsel * 32768 + band * 8192 + (wv << 10));
  };
  auto issueB = [&](int t1, int bsel, int band) {
    long long kbB = (long long)(t1 << 6) * 2;
    gload16(bP[band] + kbB, smem + 65536 + bsel * 32768 + band * 8192 + (wv << 10));
  };

  f32x4 acc[8][4];
  #pragma unroll
  for (int m = 0; m < 8; ++m)
    #pragma unroll
    for (int n = 0; n < 4; ++n) acc[m][n] = (f32x4){0.f, 0.f, 0.f, 0.f};

  int nt = Ksz >> 6;
  // prologue: tile 0 in canonical order [B0 B1 B2 B3 A0 A2 A1 A3]
  issueB(0, 0, 0); issueB(0, 0, 1); issueB(0, 0, 2); issueB(0, 0, 3);
  issueA(0, 0, 0); issueA(0, 0, 2); issueA(0, 0, 1); issueA(0, 0, 3);
  asm volatile("s_waitcnt vmcnt(2)" ::: "memory");  // B all + A bands 0,2 landed
  __builtin_amdgcn_s_barrier();

  for (int t = 0; t < nt; ++t) {
    int cur = t & 1;
    int nb = cur ^ 1;
    const char* sa = smem + cur * 32768;
    const char* sb = smem + 65536 + cur * 32768;
    bool pf = (t + 1 < nt);

    // tile top: all B fragments (bands 0..3 guaranteed by boundary wait)
    s16x8 bfr[4][2];
    #pragma unroll
    for (int n = 0; n < 4; ++n) {
      bfr[n][0] = *(const s16x8*)(sb + (brow0 + n * 16) * 128 + ksw0);
      bfr[n][1] = *(const s16x8*)(sb + (brow0 + n * 16) * 128 + ksw1);
    }

    #pragma unroll
    for (int p = 0; p < 4; ++p) {
      // issue next tile's group for this phase
      if (pf) {
        if (p == 0)      { issueB(t + 1, nb, 0); issueB(t + 1, nb, 1); }
        else if (p == 1) { issueB(t + 1, nb, 2); issueB(t + 1, nb, 3); }
        else if (p == 2) { issueA(t + 1, nb, 0); issueA(t + 1, nb, 2); }
        else             { issueA(t + 1, nb, 1); issueA(t + 1, nb, 3); }
      }
      // A fragments for this phase (p<2: bands wr*2; p>=2: bands wr*2+1, covered by mid-wait)
      s16x8 af0_0 = *(const s16x8*)(sa + (arow0 + (p * 2 + 0) * 16) * 128 + ksw0);
      s16x8 af0_1 = *(const s16x8*)(sa + (arow0 + (p * 2 + 0) * 16) * 128 + ksw1);
      s16x8 af1_0 = *(const s16x8*)(sa + (arow0 + (p * 2 + 1) * 16) * 128 + ksw0);
      s16x8 af1_1 = *(const s16x8*)(sa + (arow0 + (p * 2 + 1) * 16) * 128 + ksw1);
      __builtin_amdgcn_s_barrier();
      asm volatile("s_waitcnt lgkmcnt(0)" ::: "memory");
      __builtin_amdgcn_s_setprio(1);
      #pragma unroll
      for (int n = 0; n < 4; ++n) {
        acc[p*2+0][n] = __builtin_amdgcn_mfma_f32_16x16x32_bf16(af0_0, bfr[n][0], acc[p*2+0][n], 0, 0, 0);
        acc[p*2+0][n] = __builtin_amdgcn_mfma_f32_16x16x32_bf16(af0_1, bfr[n][1], acc[p*2+0][n], 0, 0, 0);
        acc[p*2+1][n] = __builtin_amdgcn_mfma_f32_16x16x32_bf16(af1_0, bfr[n][0], acc[p*2+1][n], 0, 0, 0);
        acc[p*2+1][n] = __builtin_amdgcn_mfma_f32_16x16x32_bf16(af1_1, bfr[n][1], acc[p*2+1][n], 0, 0, 0);
      }
      __builtin_amdgcn_s_setprio(0);
      if (p == 1) {
        // mid-wait: A bands 1,3 of cur must land before phases 2-3 read them
        if (pf) asm volatile("s_waitcnt vmcnt(4)" ::: "memory");
        else    asm volatile("s_waitcnt vmcnt(0)" ::: "memory");
      } else if (p == 3) {
        // boundary: next tile's B all + A bands 0,2 must land
        if (pf) asm volatile("s_waitcnt vmcnt(2)" ::: "memory");
      }
      __builtin_amdgcn_s_barrier();
    }
  }

  int rb = tm * 256 + wr * 128 + (lnh << 2);
  if (MODE == 0) {
    u16* Cp = (u16*)C;
    #pragma unroll
    for (int m = 0; m < 8; ++m)
      #pragma unroll
      for (int n = 0; n < 4; ++n) {
        int col = tn * 256 + wc * 64 + n * 16 + lnl;
        #pragma unroll
        for (int v = 0; v < 4; ++v)
          Cp[(size_t)(rb + m * 16 + v) * ldc + col] = f2bf(acc[m][n][v]);
      }
  } else if (MODE == 1) {
    u16* Cp = (u16*)C + (size_t)e * sC;
    #pragma unroll
    for (int m = 0; m < 8; ++m)
      #pragma unroll
      for (int n = 0; n < 2; ++n) {
        int col = tn * 128 + wc * 32 + n * 16 + lnl;
        #pragma unroll
        for (int v = 0; v < 4; ++v) {
          float g = acc[m][n][v];
          float u = acc[m][n + 2][v];
          float sg = g / (1.f + __expf(-g));
          Cp[(size_t)(rb + m * 16 + v) * ldc + col] = f2bf(sg * u);
        }
      }
  } else if (MODE == 2) {
    u16* Cp = (u16*)C;
    #pragma unroll
    for (int m = 0; m < 8; ++m)
      #pragma unroll
      for (int v = 0; v < 4; ++v) {
        int gr = rb + m * 16 + v;
        int i = dst[e * CAPv + gr];
        if (i >= 0) {
          #pragma unroll
          for (int n = 0; n < 4; ++n)
            Cp[(size_t)i * Dv + tn * 256 + wc * 64 + n * 16 + lnl] = f2bf(acc[m][n][v]);
        }
      }
  } else {
    u16* Cp = (u16*)C;
    #pragma unroll
    for (int m = 0; m < 8; ++m)
      #pragma unroll
      for (int n = 0; n < 4; ++n) {
        int col = tn * 256 + wc * 64 + n * 16 + lnl;
        #pragma unroll
        for (int v = 0; v < 4; ++v) {
          float xg = acc[m][n][v];
          float gl = 0.5f * xg * (1.f + erff(xg * 0.70710678118654752f));
          Cp[(size_t)(rb + m * 16 + v) * ldc + col] = f2bf(gl);
        }
      }
  }
}

// ---------------- 128x128 GEMM (small final projection, f32 out) ----------------
template<int MODE>
__global__ __launch_bounds__(256) void gemm128(
    const u16* __restrict__ A, const u16* __restrict__ A2, int splitK,
    const u16* __restrict__ B, void* __restrict__ C,
    const int* __restrict__ dst,
    int Ksz, int lda, int ldb, int ldc, int ntm,
    size_t sA, size_t sB, size_t sC)
{
  __shared__ char smem[32768];
  int e = blockIdx.y;
  int bid = blockIdx.x;
  int tm = bid % ntm, tn = bid / ntm;
  const u16* Ae  = A  + (size_t)e * sA;
  const u16* Be  = B  + (size_t)e * sB;
  int tid = threadIdx.x, wv = tid >> 6, ln = tid & 63;

  const char* aP[4]; const char* bP[4];
  unsigned aL[4], bL[4];
  #pragma unroll
  for (int r = 0; r < 4; ++r) {
    int lb = r * 4096 + tid * 16;
    int row = lb >> 7;
    int colb = (lb & 127) ^ ((row & 7) << 4);
    aP[r] = (const char*)(Ae + (size_t)(tm * 128 + row) * lda) + colb;
    bP[r] = (const char*)(Be + (size_t)(tn * 128 + row) * ldb) + colb;
    aL[r] = r * 4096 + wv * 1024;
    bL[r] = 16384 + r * 4096 + wv * 1024;
  }

  f32x4 acc[2][8];
  #pragma unroll
  for (int m = 0; m < 2; ++m)
    #pragma unroll
    for (int n = 0; n < 8; ++n) acc[m][n] = (f32x4){0.f, 0.f, 0.f, 0.f};

  for (int k0 = 0; k0 < Ksz; k0 += 64) {
    size_t kb = (size_t)k0 * 2;
    #pragma unroll
    for (int r = 0; r < 4; ++r) gload16(aP[r] + kb, smem + aL[r]);
    #pragma unroll
    for (int r = 0; r < 4; ++r) gload16(bP[r] + kb, smem + bL[r]);
    __syncthreads();
    #pragma unroll
    for (int ks = 0; ks < 2; ++ks) {
      int kbyte = ks * 64 + ((ln >> 4) << 4);
      s16x8 av[2];
      #pragma unroll
      for (int m = 0; m < 2; ++m) {
        int row = wv * 32 + m * 16 + (ln & 15);
        av[m] = *(const s16x8*)(smem + (row << 7) + (kbyte ^ ((row & 7) << 4)));
      }
      #pragma unroll
      for (int n = 0; n < 8; ++n) {
        int row = n * 16 + (ln & 15);
        s16x8 bv = *(const s16x8*)(smem + 16384 + (row << 7) + (kbyte ^ ((row & 7) << 4)));
        acc[0][n] = __builtin_amdgcn_mfma_f32_16x16x32_bf16(av[0], bv, acc[0][n], 0, 0, 0);
        acc[1][n] = __builtin_amdgcn_mfma_f32_16x16x32_bf16(av[1], bv, acc[1][n], 0, 0, 0);
      }
    }
    __syncthreads();
  }

  int rbase = tm * 128 + wv * 32 + ((ln >> 4) << 2);
  int cb = (ln & 15);
  float* Cp = (float*)C;
  #pragma unroll
  for (int m = 0; m < 2; ++m)
    #pragma unroll
    for (int n = 0; n < 8; ++n)
      #pragma unroll
      for (int v = 0; v < 4; ++v)
        Cp[(size_t)(rbase + m * 16 + v) * ldc + tn * 128 + n * 16 + cb] = acc[m][n][v];
  (void)A2; (void)splitK; (void)dst; (void)sC;
}

// ---------------- per-token scores + masked softmax + Cmsg ----------------
__global__ __launch_bounds__(256) void scores_kernel(
    const u16* __restrict__ MQ, const u16* __restrict__ KK,
    const int* __restrict__ keep, u16* __restrict__ Cmsg)
{
  int wv = threadIdx.x >> 6, ln = threadIdx.x & 63;
  int n = blockIdx.x * 4 + wv;
  const u16* m0 = MQ + (size_t)(2 * n) * 2048;
  const u16* m1 = MQ + (size_t)(2 * n + 1) * 2048;
  const u16* q0 = m0 + 1024;
  const u16* q1 = m1 + 1024;
  const u16* k0p = KK + (size_t)(2 * n) * 1024;
  const u16* k1p = KK + (size_t)(2 * n + 1) * 1024;
  float s00 = 0, s01 = 0, s10 = 0, s11 = 0;
  #pragma unroll
  for (int j = 0; j < 2; ++j) {
    int d0 = ln * 16 + j * 8;
    u16x8 a0 = *(const u16x8*)(q0 + d0);
    u16x8 a1 = *(const u16x8*)(q1 + d0);
    u16x8 b0 = *(const u16x8*)(k0p + d0);
    u16x8 b1 = *(const u16x8*)(k1p + d0);
    #pragma unroll
    for (int t = 0; t < 8; ++t) {
      float fa0 = bf2f(a0[t]), fa1 = bf2f(a1[t]);
      float fb0 = bf2f(b0[t]), fb1 = bf2f(b1[t]);
      s00 += fa0 * fb0; s01 += fa0 * fb1; s10 += fa1 * fb0; s11 += fa1 * fb1;
    }
  }
  #pragma unroll
  for (int off = 32; off >= 1; off >>= 1) {
    s00 += __shfl_xor(s00, off, 64);
    s01 += __shfl_xor(s01, off, 64);
    s10 += __shfl_xor(s10, off, 64);
    s11 += __shfl_xor(s11, off, 64);
  }
  const float inv = 0.03125f;
  int kp0 = keep[2 * n], kp1 = keep[2 * n + 1];
  float A00, A01, A10, A11;
  {
    float v0 = kp0 ? s00 * inv : -1e9f;
    float v1 = (kp0 && kp1) ? s01 * inv : -1e9f;
    float mx = fmaxf(v0, v1);
    float e0 = expf(v0 - mx), e1 = expf(v1 - mx);
    float den = e0 + e1;
    float a0 = kp0 ? e0 / den : 0.f;
    float a1 = (kp0 && kp1) ? e1 / den : 0.f;
    float s = fmaxf(a0 + a1, 1e-12f);
    A00 = a0 / s; A01 = a1 / s;
  }
  {
    float v0 = (kp1 && kp0) ? s10 * inv : -1e9f;
    float v1 = kp1 ? s11 * inv : -1e9f;
    float mx = fmaxf(v0, v1);
    float e0 = expf(v0 - mx), e1 = expf(v1 - mx);
    float den = e0 + e1;
    float a0 = (kp1 && kp0) ? e0 / den : 0.f;
    float a1 = kp1 ? e1 / den : 0.f;
    float s = fmaxf(a0 + a1, 1e-12f);
    A10 = a0 / s; A11 = a1 / s;
  }
  u16* c0 = Cmsg + (size_t)(2 * n) * 1024;
  u16* c1 = Cmsg + (size_t)(2 * n + 1) * 1024;
  #pragma unroll
  for (int j = 0; j < 2; ++j) {
    int d0 = ln * 16 + j * 8;
    u16x8 x0 = *(const u16x8*)(m0 + d0);
    u16x8 x1 = *(const u16x8*)(m1 + d0);
    u16x8 o0, o1;
    #pragma unroll
    for (int t = 0; t < 8; ++t) {
      float f0 = bf2f(x0[t]), f1 = bf2f(x1[t]);
      o0[t] = f2bf(A00 * f0 + A01 * f1);
      o1[t] = f2bf(A10 * f0 + A11 * f1);
    }
    *(u16x8*)(c0 + d0) = o0;
    *(u16x8*)(c1 + d0) = o1;
  }
}

// ---------------- combine ----------------
__global__ __launch_bounds__(256) void combine_kernel(
    const u16* __restrict__ sel, const u16* __restrict__ upd,
    const int* __restrict__ keep, const float* __restrict__ tkprob,
    u16* __restrict__ fusedp)
{
  int n = blockIdx.x;
  int t = threadIdx.x;
  float kp0 = keep[2 * n] ? 1.f : 0.f, kp1 = keep[2 * n + 1] ? 1.f : 0.f;
  float p0 = tkprob[2 * n] * kp0, p1 = tkprob[2 * n + 1] * kp1;
  float s = fmaxf(p0 + p1, 1e-12f);
  float w0 = p0 / s, w1 = p1 / s;
  int d0 = t * 4;
  u16x4 s0 = *(const u16x4*)(sel + (size_t)(2 * n) * Dv + d0);
  u16x4 s1 = *(const u16x4*)(sel + (size_t)(2 * n + 1) * Dv + d0);
  u16x4 u0 = *(const u16x4*)(upd + (size_t)(2 * n) * Dv + d0);
  u16x4 u1 = *(const u16x4*)(upd + (size_t)(2 * n + 1) * Dv + d0);
  u16x4 o;
  #pragma unroll
  for (int j = 0; j < 4; ++j) {
    float r0 = (bf2f(s0[j]) + bf2f(u0[j])) * kp0;
    float r1 = (bf2f(s1[j]) + bf2f(u1[j])) * kp1;
    o[j] = f2bf(w0 * r0 + w1 * r1);
  }
  *(u16x4*)(fusedp + (size_t)n * Dv + d0) = o;
}

extern "C" void kernel_launch(void* const* d_in, const int* in_sizes, int n_in,
                              void* d_out, int out_size, void* d_ws, size_t ws_size,
                              hipStream_t stream) {
  const float* x      = (const float*)d_in[0];
  const float* gate_w = (const float*)d_in[1];
  const float* w13    = (const float*)d_in[2];
  const float* w2     = (const float*)d_in[3];
  const float* msg_w  = (const float*)d_in[4];
  const float* q_w    = (const float*)d_in[5];
  const float* k_w    = (const float*)d_in[6];
  const float* upd_w1 = (const float*)d_in[7];
  const float* upd_w2 = (const float*)d_in[8];
  const float* o_w    = (const float*)d_in[9];
  float* out = (float*)d_out;
  float* outAux = out + (size_t)Nv * Dv;
  float* outIdx = outAux + 1;

  char* ws = (char*)d_ws;
  const size_t MBc = 1ull << 20;
  int*   tkidx  = (int*)(ws + 0);
  float* tkprob = (float*)(ws + 32768);
  int*   keepA  = (int*)(ws + 65536);
  int*   dstNK  = (int*)(ws + 98304);
  float* red    = (float*)(ws + 143360);
  // phase A:
  u16* BUF   = (u16*)(ws + 1 * MBc);
  u16* ACT   = (u16*)(ws + 21 * MBc);
  u16* W13B  = (u16*)(ws + 76 * MBc);
  u16* W2B   = (u16*)(ws + 76 * MBc);
  u16* SEL   = (u16*)(ws + 120 * MBc);
  u16* MSGQB = (u16*)(ws + 136 * MBc);
  u16* KB    = (u16*)(ws + 140 * MBc);
  u16* OB    = (u16*)(ws + 142 * MBc);
  u16* UPD1B = (u16*)(ws + 144 * MBc);
  u16* UPD2B = (u16*)(ws + 152 * MBc);
  // phase B:
  u16* MQ    = (u16*)(ws + 1 * MBc);
  u16* KKb   = (u16*)(ws + 33 * MBc);
  u16* CMSG  = (u16*)(ws + 49 * MBc);
  u16* G1B   = (u16*)(ws + 65 * MBc);
  u16* UPD   = (u16*)(ws + 97 * MBc);
  u16* FUSEDP= (u16*)(ws + 1 * MBc);

  hipMemsetAsync(red, 0, 68, stream);
  hipMemsetAsync(dstNK, 0xFF, Ev * CAPv * 4, stream);

  router_kernel<<<Nv / 4, 256, 0, stream>>>(x, gate_w, tkidx, tkprob, red, outIdx);
  aux_kernel<<<1, 1, 0, stream>>>(red, outAux);
  rank_kernel<<<1, 256, 0, stream>>>(tkidx, keepA, dstNK);
  pack_kernel<<<(Ev * CAPv) / 4, 256, 0, stream>>>(x, dstNK, BUF);

  // G1: convert all w13, one batched SwiGLU GEMM
  tconv_kernel<<<dim3(TH2v / 64, Dv / 64, Ev), 256, 0, stream>>>(w13, W13B, Dv, TH2v);
  gemm256<1><<<dim3((CAPv / 256) * (Hv / 128), Ev), 512, 0, stream>>>(
      BUF, BUF, 1 << 30, W13B, (void*)ACT, nullptr,
      Dv, Dv, Dv, Hv, CAPv / 256, (size_t)CAPv * Dv, (size_t)TH2v * Dv, (size_t)CAPv * Hv);

  hipMemsetAsync(SEL, 0, (size_t)NKv * Dv * 2, stream);
  tconv_kernel<<<dim3(Dv / 64, Hv / 64, Ev), 256, 0, stream>>>(w2, W2B, Hv, Dv);
  tconv_kernel<<<dim3(16, 16, 1), 256, 0, stream>>>(msg_w, MSGQB, Dv, Dv);
  tconv_kernel<<<dim3(16, 16, 1), 256, 0, stream>>>(q_w, MSGQB + (size_t)Dv * Dv, Dv, Dv);
  tconv_kernel<<<dim3(16, 16, 1), 256, 0, stream>>>(k_w, KB, Dv, Dv);
  tconv_kernel<<<dim3(16, 16, 1), 256, 0, stream>>>(o_w, OB, Dv, Dv);
  tconv_kernel<<<dim3(32, 32, 1), 256, 0, stream>>>(upd_w1, UPD1B, 2048, 2048);
  tconv_kernel<<<dim3(16, 32, 1), 256, 0, stream>>>(upd_w2, UPD2B, 2048, Dv);

  // G2: GEMM + scatter into SEL
  gemm256<2><<<dim3((CAPv / 256) * (Dv / 256), Ev), 512, 0, stream>>>(
      ACT, ACT, 1 << 30, W2B, (void*)SEL, dstNK,
      Hv, Hv, Hv, Dv, CAPv / 256, (size_t)CAPv * Hv, (size_t)Dv * Hv, 0);

  // collaboration: fused [M|Q] GEMM, then Kk GEMM, then scores
  gemm256<0><<<dim3(32 * 8, 1), 512, 0, stream>>>(SEL, SEL, 1 << 30, MSGQB, (void*)MQ, nullptr,
      Dv, Dv, Dv, 2048, 32, 0, 0, 0);
  gemm256<0><<<dim3(32 * 4, 1), 512, 0, stream>>>(MQ, MQ, 1 << 30, KB, (void*)KKb, nullptr,
      Dv, 2048, Dv, Dv, 32, 0, 0, 0);
  scores_kernel<<<Nv / 4, 256, 0, stream>>>(MQ, KKb, keepA, CMSG);

  // update MLP: cat = [SEL | CMSG] via split-K A, gelu fused
  gemm256<3><<<dim3(32 * 8, 1), 512, 0, stream>>>(SEL, CMSG, Dv, UPD1B, (void*)G1B, nullptr,
      2048, Dv, 2048, 2048, 32, 0, 0, 0);
  gemm256<0><<<dim3(32 * 4, 1), 512, 0, stream>>>(G1B, G1B, 1 << 30, UPD2B, (void*)UPD, nullptr,
      2048, 2048, 2048, Dv, 32, 0, 0, 0);

  combine_kernel<<<Nv, 256, 0, stream>>>(SEL, UPD, keepA, tkprob, FUSEDP);

  gemm128<4><<<dim3(32 * 8, 1), 256, 0, stream>>>(FUSEDP, FUSEDP, Dv, OB, (void*)out, nullptr,
      Dv, Dv, Dv, Dv, 32, 0, 0, 0);

  (void)in_sizes; (void)n_in; (void)out_size; (void)ws_size;
}